// Round 1
// baseline (7555.669 us; speedup 1.0000x reference)
//
#include <hip/hip_runtime.h>
#include <math.h>

// Round 6: occupancy doubling via 2-wave-per-batch M-split.
//  - Grid was capped at 2048 waves (1 wave/batch) = 2 waves/SIMD (Occ 21%).
//    Split each batch's [LD=32] rows across a 2-wave / 128-thread block:
//    wave sb owns rows sb*16..sb*16+15 (mt=sb). LN stats, LN apply, channel
//    mixing (mm3/mm4), head, output: all wave-local. Token mixing reduces
//    over the split axis -> exchange y (LN1 out) and h (mm1 out) through
//    LDS with 2 barriers/layer (same count as before, now 2-wave barriers).
//  - wbufC/wbufO block staging + biasL dropped (weights/bias frags read
//    direct from ws/global; L1-resident). LDS 74KB -> 16KB => 8 blocks/CU.
//  - phys MLP hoisted to a parallel pre-kernel over B*T; p stored f16 in
//    d_out's own [b,t] 128B slots (read at step start, overwritten by the
//    step's output at step end; cross-wave ordering via barrier A).
//
// Fragment layouts (gfx950, verified rounds 2-5, bit-identical here):
//   A[m=lane&15][k=(lane>>4)*8+j], B[k=(lane>>4)*8+j][n=lane&15],
//   C: col=lane&15, row=(lane>>4)*4+reg.

namespace {
constexpr int Tt = 256, NL = 3;

typedef float    f32x4 __attribute__((ext_vector_type(4)));
typedef _Float16 half2 __attribute__((ext_vector_type(2)));
typedef _Float16 h16x4 __attribute__((ext_vector_type(4)));
typedef _Float16 h16x8 __attribute__((ext_vector_type(8)));

#define MFMA16(a, b, c) __builtin_amdgcn_mfma_f32_16x16x32_f16((a), (b), (c), 0, 0, 0)

__device__ __forceinline__ half2 h2c(float v) { return (half2)((_Float16)v); }
__device__ __forceinline__ half2 pkrtz(float a, float b) {
    return __builtin_bit_cast(half2, __builtin_amdgcn_cvt_pkrtz(a, b));
}
__device__ __forceinline__ void st4h(short* p, half2 a, half2 b) {
    uint2 v;
    v.x = __builtin_bit_cast(unsigned int, a);
    v.y = __builtin_bit_cast(unsigned int, b);
    *(uint2*)p = v;
}
// packed f16 GELU, no transcendentals. s scaled by 1/8 to keep c4 normal in f16.
__device__ __forceinline__ half2 gelu_pk(half2 x) {
    half2 tc = __builtin_elementwise_min(__builtin_elementwise_max(x, h2c(-3.0f)), h2c(3.0f));
    half2 s = (tc * tc) * h2c(0.125f);
    half2 p = s * h2c(0.1455169f) + h2c(-0.446340f);
    p = s * p + h2c(0.604927f);
    p = s * p + h2c(-0.529702f);
    p = s * p + h2c(0.3989423f);
    return x * (h2c(0.5f) + tc * p);
}
// scalar f32 version (phys MLP pre-pass)
__device__ __forceinline__ float gelu_f(float x) {
    float tc = fminf(fmaxf(x, -3.f), 3.f);
    float s = tc * tc;
    float p = fmaf(s, 3.55266e-5f, -8.71758e-4f);
    p = fmaf(s, p, 9.45198e-3f);
    p = fmaf(s, p, -6.62128e-2f);
    p = fmaf(s, p, 0.3989423f);
    return x * fmaf(tc, p, 0.5f);
}
// sum across the 16-lane DPP row (all lanes get the total)
__device__ __forceinline__ float rowsum16(float x) {
    x += __builtin_bit_cast(float, __builtin_amdgcn_update_dpp(0, __builtin_bit_cast(int, x), 0x121, 0xf, 0xf, false));
    x += __builtin_bit_cast(float, __builtin_amdgcn_update_dpp(0, __builtin_bit_cast(int, x), 0x122, 0xf, 0xf, false));
    x += __builtin_bit_cast(float, __builtin_amdgcn_update_dpp(0, __builtin_bit_cast(int, x), 0x124, 0xf, 0xf, false));
    x += __builtin_bit_cast(float, __builtin_amdgcn_update_dpp(0, __builtin_bit_cast(int, x), 0x128, 0xf, 0xf, false));
    return x;
}

__device__ __forceinline__ short f2h(float x) {
    return __builtin_bit_cast(short, (_Float16)x);
}

// ws layout: shorts(f16) tiWF[0,6144) toWF[6144,12288) ciWF[12288,36864) coWF[36864,61440)
//            then fp32 W2F[4096] at short index 61440 (unused by scan now, kept for layout)
__global__ void lno_prep(const float* __restrict__ tiW, const float* __restrict__ toW,
                         const float* __restrict__ ciW, const float* __restrict__ coW,
                         const float* __restrict__ physW2, short* __restrict__ wsf) {
    int id = blockIdx.x * 256 + threadIdx.x;  // 0..65535
    if (id < 6144) {            // A1: m=th, k=ld
        int j = id & 7, lane = (id >> 3) & 63, g = id >> 9;
        int il = g >> 2, u = g & 3;
        int m = u * 16 + (lane & 15), k = (lane >> 4) * 8 + j;
        wsf[id] = f2h(tiW[il * 2048 + k * 64 + m]);
    } else if (id < 12288) {    // A2: m=ld, k=th
        int t = id - 6144;
        int j = t & 7, lane = (t >> 3) & 63, g = t >> 9;
        int il = g >> 2, mt2 = (g >> 1) & 1, ks = g & 1;
        int m = mt2 * 16 + (lane & 15), k = ks * 32 + (lane >> 4) * 8 + j;
        wsf[id] = f2h(toW[il * 2048 + k * 32 + m]);
    } else if (id < 36864) {    // A3: m=ch, k=w
        int t = id - 12288;
        int j = t & 7, lane = (t >> 3) & 63, g = t >> 9;
        int il = g >> 4, mtc = (g >> 1) & 7, ks = g & 1;
        int m = mtc * 16 + (lane & 15), k = ks * 32 + (lane >> 4) * 8 + j;
        wsf[id] = f2h(ciW[il * 8192 + k * 128 + m]);
    } else if (id < 61440) {    // B4: k=ch, n=w
        int t = id - 36864;
        int j = t & 7, lane = (t >> 3) & 63, g = t >> 9;
        int il = g >> 4, nt = (g >> 2) & 3, ks = g & 3;
        int n = nt * 16 + (lane & 15), k = ks * 32 + (lane >> 4) * 8 + j;
        wsf[id] = f2h(coW[il * 8192 + k * 64 + n]);
    } else if (id < 65536) {    // W2F fp32 [w][k]
        int t = id - 61440;
        int w = t >> 6, k = t & 63;
        ((float*)(wsf + 61440))[t] = physW2[k * 64 + w];
    }
}

// phys MLP pre-pass: p[b,t,w] = gelu(phys@W1+b1)@W2+b2, stored f16 in d_out's
// [b,t] 128B slot, permuted so lane (q,c) in the scan reads its 4 values
// {w = nt*16+c} as one 8B load: slot j = (w&15)*4 + (w>>4).
__global__ void lno_phys(const float* __restrict__ phys, const float* __restrict__ physW1,
                         const float* __restrict__ physb1, const float* __restrict__ physW2,
                         const float* __restrict__ physb2, short* __restrict__ pout) {
    __shared__ float hsh[4][64];
    const int lane = threadIdx.x & 63, wv = threadIdx.x >> 6;
    const size_t bt = (size_t)blockIdx.x * 4 + wv;   // < 2048*256
    const float* pt = phys + bt * 8;
    float4 px0 = *(const float4*)pt, px1 = *(const float4*)(pt + 4);
    float a = physb1[lane];
    a = fmaf(px0.x, physW1[0 * 64 + lane], a);
    a = fmaf(px0.y, physW1[1 * 64 + lane], a);
    a = fmaf(px0.z, physW1[2 * 64 + lane], a);
    a = fmaf(px0.w, physW1[3 * 64 + lane], a);
    a = fmaf(px1.x, physW1[4 * 64 + lane], a);
    a = fmaf(px1.y, physW1[5 * 64 + lane], a);
    a = fmaf(px1.z, physW1[6 * 64 + lane], a);
    a = fmaf(px1.w, physW1[7 * 64 + lane], a);
    hsh[wv][lane] = gelu_f(a);   // wave-local exchange; compiler orders via lgkmcnt
    float acc = physb2[lane];
#pragma unroll
    for (int k = 0; k < 64; ++k) acc = fmaf(hsh[wv][k], physW2[k * 64 + lane], acc);
    pout[bt * 64 + (lane & 15) * 4 + (lane >> 4)] = f2h(acc);
}

// block = 128 threads = 2 waves = 1 batch. Wave sb owns latent rows sb*16..+15.
// NOTE: pbuf and out alias (both d_out). Deliberately NOT __restrict__: p[b,t]
// is consumed (vmcnt-waited) before barrier A of step t; out[b,t] is written
// after all of step t's barriers -> read-before-overwrite is safe per wave and
// across the wave pair.
__global__ __launch_bounds__(128, 4) void lno_scan(
    const float* __restrict__ latents, const float* __restrict__ pos_emb,
    const float* __restrict__ tokW,    const float* __restrict__ tokb,
    const float* __restrict__ tn_g,    const float* __restrict__ tn_b,
    const float* __restrict__ tib,     const float* __restrict__ tob,
    const float* __restrict__ cn_g,    const float* __restrict__ cn_b,
    const float* __restrict__ cib,     const float* __restrict__ cob,
    const float* __restrict__ hn_g,    const float* __restrict__ hn_b,
    const float* __restrict__ headW,   const float* __restrict__ headb,
    const short* __restrict__ wsf,     const short* pbuf, float* out)
{
    __shared__ __align__(16) short yB[2048];      // y exchange: full [32ld x 64w] frags
    __shared__ __align__(16) short hB[4096];      // h exchange: two K-halves (sb writes half sb)
    __shared__ __align__(16) short scr[2][1024];  // per-wave y2/h2 scratch (wave-local)

    const short* tiWF = wsf;
    const short* toWF = wsf + 6144;
    const short* ciWF = wsf + 12288;
    const short* coWF = wsf + 36864;

    const int tid = threadIdx.x, lane = tid & 63, sb = tid >> 6;
    const int q = lane >> 4, c = lane & 15;
    const int b = blockIdx.x;
    short* sc = scr[sb];

    // ---- hoisted per-lane constants ----
    float tokw_r[4], tokb_r[4], gh_r[4];
#pragma unroll
    for (int nt = 0; nt < 4; ++nt) {
        tokw_r[nt] = tokW[nt * 16 + c];
        tokb_r[nt] = tokb[nt * 16 + c];
        gh_r[nt]   = hn_g[nt * 16 + c] * headW[nt * 16 + c];
    }
    float bhp = 0.f;
#pragma unroll
    for (int nt = 0; nt < 4; ++nt) bhp = fmaf(hn_b[nt * 16 + c], headW[nt * 16 + c], bhp);
    const float bh = rowsum16(bhp) + headb[0];

    float pe_r[4][4];
#pragma unroll
    for (int nt = 0; nt < 4; ++nt)
#pragma unroll
        for (int r = 0; r < 4; ++r)
            pe_r[nt][r] = pos_emb[(sb * 16 + q * 4 + r) * 64 + nt * 16 + c];

    f32x4 cur = *(const f32x4*)(latents + b * 32 + sb * 16 + q * 4);
    f32x4 tok[4];

    auto stats = [&](f32x4& mean, f32x4& rsig) {
#pragma unroll
        for (int r = 0; r < 4; ++r) {
            float s = (tok[0][r] + tok[1][r]) + (tok[2][r] + tok[3][r]);
            float qq = tok[0][r] * tok[0][r];
            qq = fmaf(tok[1][r], tok[1][r], qq);
            qq = fmaf(tok[2][r], tok[2][r], qq);
            qq = fmaf(tok[3][r], tok[3][r], qq);
            s = rowsum16(s); qq = rowsum16(qq);
            float m = s * 0.015625f;
            float v = fmaf(-m, m, qq * 0.015625f);
            mean[r] = m;
            rsig[r] = __builtin_amdgcn_rsqf(v + 1e-5f);
        }
    };

#pragma unroll 1
    for (int t = 0; t < Tt; ++t) {
        // ======== p load (precomputed phys MLP) + token init ========
        const h16x4 pv = *(const h16x4*)(pbuf + ((size_t)b * Tt + t) * 64 + c * 4);
#pragma unroll
        for (int nt = 0; nt < 4; ++nt) {
            const float basep = tokb_r[nt] + (float)pv[nt];
#pragma unroll
            for (int r = 0; r < 4; ++r)
                tok[nt][r] = fmaf(cur[r], tokw_r[nt], basep + pe_r[nt][r]);
        }

#pragma unroll 1
        for (int il = 0; il < NL; ++il) {
            // ======== token mixing ========
            f32x4 mean, rsig;
            stats(mean, rsig);
#pragma unroll
            for (int nt = 0; nt < 4; ++nt) {
                const float tng = tn_g[il * 64 + nt * 16 + c];
                const float tnb = tn_b[il * 64 + nt * 16 + c];
                float y0 = fmaf((tok[nt][0] - mean[0]) * rsig[0], tng, tnb);
                float y1 = fmaf((tok[nt][1] - mean[1]) * rsig[1], tng, tnb);
                float y2 = fmaf((tok[nt][2] - mean[2]) * rsig[2], tng, tnb);
                float y3 = fmaf((tok[nt][3] - mean[3]) * rsig[3], tng, tnb);
                st4h(&yB[(nt * 64 + (sb * 2 + (q >> 1)) * 16 + c) * 8 + (q & 1) * 4],
                     pkrtz(y0, y1), pkrtz(y2, y3));
            }
            __syncthreads();  // (A) yB complete (both waves)
            h16x8 yfrag[4];
#pragma unroll
            for (int nt = 0; nt < 4; ++nt) yfrag[nt] = *(const h16x8*)&yB[(nt * 64 + lane) * 8];

            // mm1: this wave produces K-half sb of h (u = sb*2+uu)
#pragma unroll
            for (int uu = 0; uu < 2; ++uu) {
                const int u = sb * 2 + uu;
                const h16x8 a1 = *(const h16x8*)(tiWF + ((il * 4 + u) * 64 + lane) * 8);
                const f32x4 bi = *(const f32x4*)(tib + il * 64 + u * 16 + q * 4);
#pragma unroll
                for (int nt = 0; nt < 4; ++nt) {
                    f32x4 acc = MFMA16(a1, yfrag[nt], bi);
                    st4h(&hB[sb * 2048 + (nt * 64 + (uu * 2 + (q >> 1)) * 16 + c) * 8 + (q & 1) * 4],
                         gelu_pk(pkrtz(acc[0], acc[1])), gelu_pk(pkrtz(acc[2], acc[3])));
                }
            }
            {   // pre-add tob (own rows); mm2 accumulates in place
                const f32x4 tb = *(const f32x4*)(tob + il * 32 + sb * 16 + q * 4);
#pragma unroll
                for (int nt = 0; nt < 4; ++nt) tok[nt] += tb;
            }
            __syncthreads();  // (B) hB complete (both halves)
            // mm2: own rows (mt=sb), both K-halves
#pragma unroll
            for (int h = 0; h < 2; ++h) {
                const h16x8 a2 = *(const h16x8*)(toWF + ((il * 4 + sb * 2 + h) * 64 + lane) * 8);
                h16x8 hf[4];
#pragma unroll
                for (int nt = 0; nt < 4; ++nt)
                    hf[nt] = *(const h16x8*)&hB[h * 2048 + (nt * 64 + lane) * 8];
#pragma unroll
                for (int nt = 0; nt < 4; ++nt) tok[nt] = MFMA16(a2, hf[nt], tok[nt]);
            }

            // ======== channel mixing (fully wave-local) ========
            stats(mean, rsig);
#pragma unroll
            for (int nt = 0; nt < 4; ++nt) {
                const float cng = cn_g[il * 64 + nt * 16 + c];
                const float cnb = cn_b[il * 64 + nt * 16 + c];
#pragma unroll
                for (int r = 0; r < 4; ++r) {
                    float v = fmaf((tok[nt][r] - mean[r]) * rsig[r], cng, cnb);
                    sc[(nt >> 1) * 512 + (q * 2 + (c >> 3) + 16 * r + 8 * (nt & 1)) * 8 + (c & 7)] = f2h(v);
                }
            }
            h16x8 b3[2];
            {
                const int lp = ((c >> 2) * 2 + (q & 1)) + 8 * ((c & 3) * 2 + (q >> 1));
#pragma unroll
                for (int ks = 0; ks < 2; ++ks) b3[ks] = *(const h16x8*)&sc[ks * 512 + lp * 8];
            }
#pragma unroll
            for (int nt = 0; nt < 4; ++nt) {  // pre-add cob; mm4 accumulates in place
                const float cv = cob[il * 64 + nt * 16 + c];
                tok[nt] += cv;
            }
            // mm3 (gelu->h2 scratch) + mm4 (into tok), split by ch-half hh
#pragma unroll
            for (int hh = 0; hh < 2; ++hh) {
#pragma unroll
                for (int mm = 0; mm < 4; ++mm) {
                    const int mtc = hh * 4 + mm;
                    const h16x8 a30 = *(const h16x8*)(ciWF + il * 8192 + (mtc * 2 + 0) * 512 + lane * 8);
                    const h16x8 a31 = *(const h16x8*)(ciWF + il * 8192 + (mtc * 2 + 1) * 512 + lane * 8);
                    const f32x4 bi3 = *(const f32x4*)(cib + il * 128 + mtc * 16 + q * 4);
                    f32x4 acc = MFMA16(a30, b3[0], bi3);
                    acc = MFMA16(a31, b3[1], acc);
                    st4h(&sc[(((mtc >> 1) & 1) * 64 + ((mtc & 1) * 2 + (q >> 1)) * 16 + c) * 8 + (q & 1) * 4],
                         gelu_pk(pkrtz(acc[0], acc[1])), gelu_pk(pkrtz(acc[2], acc[3])));
                }
                h16x8 a4[2];
#pragma unroll
                for (int kk = 0; kk < 2; ++kk) a4[kk] = *(const h16x8*)&sc[(kk * 64 + lane) * 8];
#pragma unroll
                for (int nt = 0; nt < 4; ++nt) {
                    const h16x8 b40 = *(const h16x8*)(coWF + il * 8192 + (nt * 4 + hh * 2 + 0) * 512 + lane * 8);
                    const h16x8 b41 = *(const h16x8*)(coWF + il * 8192 + (nt * 4 + hh * 2 + 1) * 512 + lane * 8);
                    tok[nt] = MFMA16(a4[0], b40, tok[nt]);
                    tok[nt] = MFMA16(a4[1], b41, tok[nt]);
                }
            }
        }  // il

        // ======== head (wave-local) ========
        {
            f32x4 mean, rsig;
            stats(mean, rsig);
#pragma unroll
            for (int r = 0; r < 4; ++r) {
                float l = (tok[0][r] - mean[r]) * gh_r[0];
                l = fmaf(tok[1][r] - mean[r], gh_r[1], l);
                l = fmaf(tok[2][r] - mean[r], gh_r[2], l);
                l = fmaf(tok[3][r] - mean[r], gh_r[3], l);
                l = rowsum16(l);
                float nv = cur[r] + fmaf(rsig[r], l, bh);
                cur[r] = fminf(fmaxf(nv, 0.f), 1.f);
            }
            if (c == 0)
                *(f32x4*)(out + ((size_t)b * Tt + t) * 32 + sb * 16 + q * 4) = cur;
        }
    }  // t
}
}  // namespace

extern "C" void kernel_launch(void* const* d_in, const int* in_sizes, int n_in,
                              void* d_out, int out_size, void* d_ws, size_t ws_size,
                              hipStream_t stream) {
    (void)in_sizes; (void)n_in; (void)ws_size; (void)out_size;
    const float* phys    = (const float*)d_in[0];
    const float* latents = (const float*)d_in[1];
    const float* pos_emb = (const float*)d_in[2];
    const float* tokW    = (const float*)d_in[3];
    const float* tokb    = (const float*)d_in[4];
    const float* physW1  = (const float*)d_in[5];
    const float* physb1  = (const float*)d_in[6];
    const float* physW2  = (const float*)d_in[7];
    const float* physb2  = (const float*)d_in[8];
    const float* tn_g    = (const float*)d_in[9];
    const float* tn_b    = (const float*)d_in[10];
    const float* tiW     = (const float*)d_in[11];
    const float* tib     = (const float*)d_in[12];
    const float* toW     = (const float*)d_in[13];
    const float* tob     = (const float*)d_in[14];
    const float* cn_g    = (const float*)d_in[15];
    const float* cn_b    = (const float*)d_in[16];
    const float* ciW     = (const float*)d_in[17];
    const float* cib     = (const float*)d_in[18];
    const float* coW     = (const float*)d_in[19];
    const float* cob     = (const float*)d_in[20];
    const float* hn_g    = (const float*)d_in[21];
    const float* hn_b    = (const float*)d_in[22];
    const float* headW   = (const float*)d_in[23];
    const float* headb   = (const float*)d_in[24];

    lno_prep<<<dim3(256), dim3(256), 0, stream>>>(tiW, toW, ciW, coW, physW2, (short*)d_ws);
    // p pre-pass into d_out (B*T = 524288 waves; 4 waves/block)
    lno_phys<<<dim3(131072), dim3(256), 0, stream>>>(phys, physW1, physb1, physW2, physb2,
                                                     (short*)d_out);
    // scan: 1 block per batch, 2 waves/block, 8 blocks/CU
    lno_scan<<<dim3(2048), dim3(128), 0, stream>>>(
        latents, pos_emb, tokW, tokb, tn_g, tn_b, tib, tob,
        cn_g, cn_b, cib, cob, hn_g, hn_b, headW, headb,
        (const short*)d_ws, (const short*)d_out, (float*)d_out);
}

// Round 2
// 6092.918 us; speedup vs baseline: 1.2401x; 1.2401x over previous
//
#include <hip/hip_runtime.h>
#include <math.h>

// Round 7: kill latency serialization.
//  - r6 post-mortem: occupancy 21->40% changed nothing (dur 8.2->8.5ms, VALU
//    57% both). Kernel is latency-bound: ~150 L2 weight loads/step/wave at
//    64 VGPR (no batching window) + 6 barriers/step coupling waves.
//  - r7: block = 512 thr = 8 waves = 8 independent batches, grid = 256 = 1
//    block/CU. ALL weight frags (120KB f16) + biases (6.5KB) staged into LDS
//    ONCE at t=0 (global_load_lds, 15 chunks/wave), then the 256-step scan
//    runs with ZERO barriers and zero steady global traffic except an 8B
//    prefetched p-load and the output store. 2 independent waves/SIMD.
//  - single 4KB scratch/wave: y -> h-halves -> LN2-scatter -> h2 reuse the
//    same buffer sequentially (operands read once into regs before overwrite;
//    same-pointer aliasing gives the compiler the ordering).
//  - __launch_bounds__(512,2): 256-VGPR budget so the compiler can batch
//    ds_read/global loads deeply (r6's 64 VGPR was the serializer).
//
// Fragment layouts (gfx950, verified rounds 2-6, bit-identical here):
//   A[m=lane&15][k=(lane>>4)*8+j], B[k=(lane>>4)*8+j][n=lane&15],
//   C: col=lane&15, row=(lane>>4)*4+reg.

namespace {
constexpr int Tt = 256, NL = 3;

typedef float    f32x4 __attribute__((ext_vector_type(4)));
typedef _Float16 half2 __attribute__((ext_vector_type(2)));
typedef _Float16 h16x4 __attribute__((ext_vector_type(4)));
typedef _Float16 h16x8 __attribute__((ext_vector_type(8)));

#define MFMA16(a, b, c) __builtin_amdgcn_mfma_f32_16x16x32_f16((a), (b), (c), 0, 0, 0)

__device__ __forceinline__ half2 h2c(float v) { return (half2)((_Float16)v); }
__device__ __forceinline__ half2 pkrtz(float a, float b) {
    return __builtin_bit_cast(half2, __builtin_amdgcn_cvt_pkrtz(a, b));
}
__device__ __forceinline__ void st4h(short* p, half2 a, half2 b) {
    uint2 v;
    v.x = __builtin_bit_cast(unsigned int, a);
    v.y = __builtin_bit_cast(unsigned int, b);
    *(uint2*)p = v;
}
// packed f16 GELU, no transcendentals. s scaled by 1/8 to keep c4 normal in f16.
__device__ __forceinline__ half2 gelu_pk(half2 x) {
    half2 tc = __builtin_elementwise_min(__builtin_elementwise_max(x, h2c(-3.0f)), h2c(3.0f));
    half2 s = (tc * tc) * h2c(0.125f);
    half2 p = s * h2c(0.1455169f) + h2c(-0.446340f);
    p = s * p + h2c(0.604927f);
    p = s * p + h2c(-0.529702f);
    p = s * p + h2c(0.3989423f);
    return x * (h2c(0.5f) + tc * p);
}
// scalar f32 version (phys MLP pre-pass)
__device__ __forceinline__ float gelu_f(float x) {
    float tc = fminf(fmaxf(x, -3.f), 3.f);
    float s = tc * tc;
    float p = fmaf(s, 3.55266e-5f, -8.71758e-4f);
    p = fmaf(s, p, 9.45198e-3f);
    p = fmaf(s, p, -6.62128e-2f);
    p = fmaf(s, p, 0.3989423f);
    return x * fmaf(tc, p, 0.5f);
}
// sum across the 16-lane DPP row (all lanes get the total)
__device__ __forceinline__ float rowsum16(float x) {
    x += __builtin_bit_cast(float, __builtin_amdgcn_update_dpp(0, __builtin_bit_cast(int, x), 0x121, 0xf, 0xf, false));
    x += __builtin_bit_cast(float, __builtin_amdgcn_update_dpp(0, __builtin_bit_cast(int, x), 0x122, 0xf, 0xf, false));
    x += __builtin_bit_cast(float, __builtin_amdgcn_update_dpp(0, __builtin_bit_cast(int, x), 0x124, 0xf, 0xf, false));
    x += __builtin_bit_cast(float, __builtin_amdgcn_update_dpp(0, __builtin_bit_cast(int, x), 0x128, 0xf, 0xf, false));
    return x;
}

__device__ __forceinline__ short f2h(float x) {
    return __builtin_bit_cast(short, (_Float16)x);
}

// ws layout: shorts(f16) tiWF[0,6144) toWF[6144,12288) ciWF[12288,36864) coWF[36864,61440)
//            then fp32 W2F[4096] at short index 61440 (unused by scan, kept for layout)
__global__ void lno_prep(const float* __restrict__ tiW, const float* __restrict__ toW,
                         const float* __restrict__ ciW, const float* __restrict__ coW,
                         const float* __restrict__ physW2, short* __restrict__ wsf) {
    int id = blockIdx.x * 256 + threadIdx.x;  // 0..65535
    if (id < 6144) {            // A1: m=th, k=ld
        int j = id & 7, lane = (id >> 3) & 63, g = id >> 9;
        int il = g >> 2, u = g & 3;
        int m = u * 16 + (lane & 15), k = (lane >> 4) * 8 + j;
        wsf[id] = f2h(tiW[il * 2048 + k * 64 + m]);
    } else if (id < 12288) {    // A2: m=ld, k=th
        int t = id - 6144;
        int j = t & 7, lane = (t >> 3) & 63, g = t >> 9;
        int il = g >> 2, mt2 = (g >> 1) & 1, ks = g & 1;
        int m = mt2 * 16 + (lane & 15), k = ks * 32 + (lane >> 4) * 8 + j;
        wsf[id] = f2h(toW[il * 2048 + k * 32 + m]);
    } else if (id < 36864) {    // A3: m=ch, k=w
        int t = id - 12288;
        int j = t & 7, lane = (t >> 3) & 63, g = t >> 9;
        int il = g >> 4, mtc = (g >> 1) & 7, ks = g & 1;
        int m = mtc * 16 + (lane & 15), k = ks * 32 + (lane >> 4) * 8 + j;
        wsf[id] = f2h(ciW[il * 8192 + k * 128 + m]);
    } else if (id < 61440) {    // B4: k=ch, n=w
        int t = id - 36864;
        int j = t & 7, lane = (t >> 3) & 63, g = t >> 9;
        int il = g >> 4, nt = (g >> 2) & 3, ks = g & 3;
        int n = nt * 16 + (lane & 15), k = ks * 32 + (lane >> 4) * 8 + j;
        wsf[id] = f2h(coW[il * 8192 + k * 64 + n]);
    } else if (id < 65536) {    // W2F fp32 [w][k]
        int t = id - 61440;
        int w = t >> 6, k = t & 63;
        ((float*)(wsf + 61440))[t] = physW2[k * 64 + w];
    }
}

// phys MLP pre-pass: p[b,t,w] = gelu(phys@W1+b1)@W2+b2, stored f16 in d_out's
// [b,t] 128B slot, permuted so scan lane (q,c) reads its 4 values {w=nt*16+c}
// as one 8B load: slot j = (w&15)*4 + (w>>4).
__global__ void lno_phys(const float* __restrict__ phys, const float* __restrict__ physW1,
                         const float* __restrict__ physb1, const float* __restrict__ physW2,
                         const float* __restrict__ physb2, short* __restrict__ pout) {
    __shared__ float hsh[4][64];
    const int lane = threadIdx.x & 63, wv = threadIdx.x >> 6;
    const size_t bt = (size_t)blockIdx.x * 4 + wv;   // < 2048*256
    const float* pt = phys + bt * 8;
    float4 px0 = *(const float4*)pt, px1 = *(const float4*)(pt + 4);
    float a = physb1[lane];
    a = fmaf(px0.x, physW1[0 * 64 + lane], a);
    a = fmaf(px0.y, physW1[1 * 64 + lane], a);
    a = fmaf(px0.z, physW1[2 * 64 + lane], a);
    a = fmaf(px0.w, physW1[3 * 64 + lane], a);
    a = fmaf(px1.x, physW1[4 * 64 + lane], a);
    a = fmaf(px1.y, physW1[5 * 64 + lane], a);
    a = fmaf(px1.z, physW1[6 * 64 + lane], a);
    a = fmaf(px1.w, physW1[7 * 64 + lane], a);
    hsh[wv][lane] = gelu_f(a);
    float acc = physb2[lane];
#pragma unroll
    for (int k = 0; k < 64; ++k) acc = fmaf(hsh[wv][k], physW2[k * 64 + lane], acc);
    pout[bt * 64 + (lane & 15) * 4 + (lane >> 4)] = f2h(acc);
}

// block = 512 thr = 8 waves = 8 independent batches. All weights+biases in LDS
// (staged once); no barriers in the t loop. pbuf and out alias (both d_out):
// p[b,t] is read at step-t start (before any out[b,t] write at step-t end),
// single owning wave -> no hazard.
__global__ __launch_bounds__(512, 2) void lno_scan(
    const float* __restrict__ latents, const float* __restrict__ pos_emb,
    const float* __restrict__ tokW,    const float* __restrict__ tokb,
    const float* __restrict__ tn_g,    const float* __restrict__ tn_b,
    const float* __restrict__ tib,     const float* __restrict__ tob,
    const float* __restrict__ cn_g,    const float* __restrict__ cn_b,
    const float* __restrict__ cib,     const float* __restrict__ cob,
    const float* __restrict__ hn_g,    const float* __restrict__ hn_b,
    const float* __restrict__ headW,   const float* __restrict__ headb,
    const short* __restrict__ wsf,     const short* pbuf, float* out)
{
    __shared__ __align__(16) short wAll[61440];     // tiL[0,6144) toL[..12288) ciL[..36864) coL[..61440)
    __shared__ __align__(16) short scr[8][2048];    // per-wave scratch: y / h-halves / y2 / h2 (sequential reuse)
    __shared__ __align__(16) float biasL[1632];     // tib[0) tob[192) cib[288) tn_g[672) tn_b[864)
                                                    // cn_g[1056) cn_b[1248) cob[1440)

    const int tid = threadIdx.x, lane = tid & 63, wv = tid >> 6;
    const int q = lane >> 4, c = lane & 15;
    const int b = blockIdx.x * 8 + wv;
    short* sc = scr[wv];

    const short* tiL = wAll;
    const short* toL = wAll + 6144;
    const short* ciL = wAll + 12288;
    const short* coL = wAll + 36864;

    // ---- one-shot weight stage: 120 chunks of 1KB, wave wv does 15 ----
    {
        const unsigned int* src = (const unsigned int*)wsf;
#pragma unroll
        for (int i = 0; i < 15; ++i) {
            const int cid = wv * 15 + i;
            __builtin_amdgcn_global_load_lds(src + cid * 256 + lane * 4,
                                             (unsigned int*)&wAll[cid * 512], 16, 0, 0);
        }
    }
    // ---- one-shot bias/LN-param stage ----
    for (int i = tid; i < 192; i += 512) {
        biasL[i] = tib[i];
        biasL[672 + i]  = tn_g[i];
        biasL[864 + i]  = tn_b[i];
        biasL[1056 + i] = cn_g[i];
        biasL[1248 + i] = cn_b[i];
        biasL[1440 + i] = cob[i];
    }
    for (int i = tid; i < 96;  i += 512) biasL[192 + i] = tob[i];
    for (int i = tid; i < 384; i += 512) biasL[288 + i] = cib[i];

    // ---- hoisted per-lane constants ----
    float tokw_r[4], tokb_r[4], gh_r[4];
#pragma unroll
    for (int nt = 0; nt < 4; ++nt) {
        tokw_r[nt] = tokW[nt * 16 + c];
        tokb_r[nt] = tokb[nt * 16 + c];
        gh_r[nt]   = hn_g[nt * 16 + c] * headW[nt * 16 + c];
    }
    float bhp = 0.f;
#pragma unroll
    for (int nt = 0; nt < 4; ++nt) bhp = fmaf(hn_b[nt * 16 + c], headW[nt * 16 + c], bhp);
    const float bh = rowsum16(bhp) + headb[0];

    float pe_r[2][4][4];
#pragma unroll
    for (int mt = 0; mt < 2; ++mt)
#pragma unroll
        for (int nt = 0; nt < 4; ++nt)
#pragma unroll
            for (int r = 0; r < 4; ++r)
                pe_r[mt][nt][r] = pos_emb[(mt * 16 + q * 4 + r) * 64 + nt * 16 + c];

    f32x4 cur8[2];
#pragma unroll
    for (int mt = 0; mt < 2; ++mt)
        cur8[mt] = *(const f32x4*)(latents + b * 32 + mt * 16 + q * 4);

    f32x4 tok[2][4];

    __syncthreads();  // weights (vmcnt drained) + biasL ready; last barrier.

    auto stats = [&](f32x4 (&mean)[2], f32x4 (&rsig)[2]) {
#pragma unroll
        for (int mt = 0; mt < 2; ++mt)
#pragma unroll
            for (int r = 0; r < 4; ++r) {
                float s = (tok[mt][0][r] + tok[mt][1][r]) + (tok[mt][2][r] + tok[mt][3][r]);
                float qq = tok[mt][0][r] * tok[mt][0][r];
                qq = fmaf(tok[mt][1][r], tok[mt][1][r], qq);
                qq = fmaf(tok[mt][2][r], tok[mt][2][r], qq);
                qq = fmaf(tok[mt][3][r], tok[mt][3][r], qq);
                s = rowsum16(s); qq = rowsum16(qq);
                float m = s * 0.015625f;
                float v = fmaf(-m, m, qq * 0.015625f);
                mean[mt][r] = m;
                rsig[mt][r] = __builtin_amdgcn_rsqf(v + 1e-5f);
            }
    };

    // p prefetch (one step ahead)
    const short* pb = pbuf + (size_t)b * Tt * 64 + c * 4;
    h16x4 pvc = *(const h16x4*)pb;

#pragma unroll 1
    for (int t = 0; t < Tt; ++t) {
        const h16x4 pv = pvc;
        if (t + 1 < Tt) pvc = *(const h16x4*)(pb + (t + 1) * 64);

        // ======== token init ========
#pragma unroll
        for (int nt = 0; nt < 4; ++nt) {
            const float basep = tokb_r[nt] + (float)pv[nt];
#pragma unroll
            for (int mt = 0; mt < 2; ++mt)
#pragma unroll
                for (int r = 0; r < 4; ++r)
                    tok[mt][nt][r] = fmaf(cur8[mt][r], tokw_r[nt], basep + pe_r[mt][nt][r]);
        }

#pragma unroll 1
        for (int il = 0; il < NL; ++il) {
            // ======== token mixing ========
            f32x4 mean[2], rsig[2];
            stats(mean, rsig);
            float tng[4], tnb[4];
#pragma unroll
            for (int nt = 0; nt < 4; ++nt) {
                tng[nt] = biasL[672 + il * 64 + nt * 16 + c];
                tnb[nt] = biasL[864 + il * 64 + nt * 16 + c];
            }
            // LN1 -> sc (y B-frags)
#pragma unroll
            for (int mt = 0; mt < 2; ++mt)
#pragma unroll
                for (int nt = 0; nt < 4; ++nt) {
                    float y0 = fmaf((tok[mt][nt][0] - mean[mt][0]) * rsig[mt][0], tng[nt], tnb[nt]);
                    float y1 = fmaf((tok[mt][nt][1] - mean[mt][1]) * rsig[mt][1], tng[nt], tnb[nt]);
                    float y2 = fmaf((tok[mt][nt][2] - mean[mt][2]) * rsig[mt][2], tng[nt], tnb[nt]);
                    float y3 = fmaf((tok[mt][nt][3] - mean[mt][3]) * rsig[mt][3], tng[nt], tnb[nt]);
                    st4h(&sc[(nt * 64 + (mt * 2 + (q >> 1)) * 16 + c) * 8 + (q & 1) * 4],
                         pkrtz(y0, y1), pkrtz(y2, y3));
                }
            h16x8 yfrag[4];
#pragma unroll
            for (int nt = 0; nt < 4; ++nt) yfrag[nt] = *(const h16x8*)&sc[(nt * 64 + lane) * 8];

            // pre-add tob (per-row) into tok; mm2 then accumulates in place
#pragma unroll
            for (int mt = 0; mt < 2; ++mt) {
                const f32x4 tb = *(const f32x4*)&biasL[192 + il * 32 + mt * 16 + q * 4];
#pragma unroll
                for (int nt = 0; nt < 4; ++nt) tok[mt][nt] += tb;
            }
            // mm1 (gelu -> sc, reusing y region after yfrag in regs) + mm2, by K-half h
#pragma unroll
            for (int h = 0; h < 2; ++h) {
#pragma unroll
                for (int uu = 0; uu < 2; ++uu) {
                    const int u = h * 2 + uu;
                    const h16x8 a1 = *(const h16x8*)(tiL + ((il * 4 + u) * 64 + lane) * 8);
                    const f32x4 bi = *(const f32x4*)&biasL[il * 64 + u * 16 + q * 4];
#pragma unroll
                    for (int nt = 0; nt < 4; ++nt) {
                        f32x4 acc = MFMA16(a1, yfrag[nt], bi);
                        st4h(&sc[(nt * 64 + (uu * 2 + (q >> 1)) * 16 + c) * 8 + (q & 1) * 4],
                             gelu_pk(pkrtz(acc[0], acc[1])), gelu_pk(pkrtz(acc[2], acc[3])));
                    }
                }
                h16x8 hf[4];
#pragma unroll
                for (int nt = 0; nt < 4; ++nt) hf[nt] = *(const h16x8*)&sc[(nt * 64 + lane) * 8];
#pragma unroll
                for (int mt = 0; mt < 2; ++mt) {
                    const h16x8 a2 = *(const h16x8*)(toL + ((il * 4 + mt * 2 + h) * 64 + lane) * 8);
#pragma unroll
                    for (int nt = 0; nt < 4; ++nt) tok[mt][nt] = MFMA16(a2, hf[nt], tok[mt][nt]);
                }
            }

            // ======== channel mixing ========
            stats(mean, rsig);
            float cng[4], cnb[4];
#pragma unroll
            for (int nt = 0; nt < 4; ++nt) {
                cng[nt] = biasL[1056 + il * 64 + nt * 16 + c];
                cnb[nt] = biasL[1248 + il * 64 + nt * 16 + c];
            }
            // LN2 -> sc (B3 frags, swizzled slots; conflict-free b16 scatter)
#pragma unroll
            for (int mt = 0; mt < 2; ++mt)
#pragma unroll
                for (int nt = 0; nt < 4; ++nt)
#pragma unroll
                    for (int r = 0; r < 4; ++r) {
                        float v = fmaf((tok[mt][nt][r] - mean[mt][r]) * rsig[mt][r], cng[nt], cnb[nt]);
                        sc[(mt * 2 + (nt >> 1)) * 512 +
                           (q * 2 + (c >> 3) + 16 * r + 8 * (nt & 1)) * 8 + (c & 7)] = f2h(v);
                    }
            h16x8 b3[4];
            {
                const int lp = ((c >> 2) * 2 + (q & 1)) + 8 * ((c & 3) * 2 + (q >> 1));
#pragma unroll
                for (int F = 0; F < 4; ++F) b3[F] = *(const h16x8*)&sc[F * 512 + lp * 8];
            }
            // pre-add cob (per-col) into tok; mm4 accumulates in place
#pragma unroll
            for (int nt = 0; nt < 4; ++nt) {
                const float cv = biasL[1440 + il * 64 + nt * 16 + c];
#pragma unroll
                for (int mt = 0; mt < 2; ++mt) tok[mt][nt] += cv;
            }

            // mm3 (gelu -> sc, reusing B3 region after b3 in regs) + mm4, by ch-half hh
#pragma unroll
            for (int hh = 0; hh < 2; ++hh) {
#pragma unroll
                for (int mm = 0; mm < 4; ++mm) {
                    const int mtc = hh * 4 + mm;
                    const h16x8 a30 = *(const h16x8*)(ciL + il * 8192 + (mtc * 2 + 0) * 512 + lane * 8);
                    const h16x8 a31 = *(const h16x8*)(ciL + il * 8192 + (mtc * 2 + 1) * 512 + lane * 8);
                    const f32x4 bi3 = *(const f32x4*)&biasL[288 + il * 128 + mtc * 16 + q * 4];
#pragma unroll
                    for (int ntl = 0; ntl < 2; ++ntl) {
                        f32x4 acc = MFMA16(a30, b3[ntl * 2 + 0], bi3);
                        acc = MFMA16(a31, b3[ntl * 2 + 1], acc);
                        st4h(&sc[((ntl * 2 + ((mtc >> 1) & 1)) * 64 +
                                  ((mtc & 1) * 2 + (q >> 1)) * 16 + c) * 8 + (q & 1) * 4],
                             gelu_pk(pkrtz(acc[0], acc[1])), gelu_pk(pkrtz(acc[2], acc[3])));
                    }
                }
                h16x8 a4[2][2];
#pragma unroll
                for (int mt = 0; mt < 2; ++mt)
#pragma unroll
                    for (int kk = 0; kk < 2; ++kk)
                        a4[mt][kk] = *(const h16x8*)&sc[((mt * 2 + kk) * 64 + lane) * 8];
#pragma unroll
                for (int nt = 0; nt < 4; ++nt) {
                    const h16x8 b40 = *(const h16x8*)(coL + il * 8192 + (nt * 4 + hh * 2 + 0) * 512 + lane * 8);
                    const h16x8 b41 = *(const h16x8*)(coL + il * 8192 + (nt * 4 + hh * 2 + 1) * 512 + lane * 8);
#pragma unroll
                    for (int mt = 0; mt < 2; ++mt) {
                        tok[mt][nt] = MFMA16(a4[mt][0], b40, tok[mt][nt]);
                        tok[mt][nt] = MFMA16(a4[mt][1], b41, tok[mt][nt]);
                    }
                }
            }
        }  // il

        // ======== head ========
        {
            f32x4 mean[2], rsig[2];
            stats(mean, rsig);
#pragma unroll
            for (int mt = 0; mt < 2; ++mt)
#pragma unroll
                for (int r = 0; r < 4; ++r) {
                    float l = (tok[mt][0][r] - mean[mt][r]) * gh_r[0];
                    l = fmaf(tok[mt][1][r] - mean[mt][r], gh_r[1], l);
                    l = fmaf(tok[mt][2][r] - mean[mt][r], gh_r[2], l);
                    l = fmaf(tok[mt][3][r] - mean[mt][r], gh_r[3], l);
                    l = rowsum16(l);
                    float nv = cur8[mt][r] + fmaf(rsig[mt][r], l, bh);
                    nv = fminf(fmaxf(nv, 0.f), 1.f);
                    cur8[mt][r] = nv;
                }
            if (c == 0) {
                float* op = out + ((size_t)b * Tt + t) * 32 + q * 4;
                *(f32x4*)(op) = cur8[0];
                *(f32x4*)(op + 16) = cur8[1];
            }
        }
    }  // t
}
}  // namespace

extern "C" void kernel_launch(void* const* d_in, const int* in_sizes, int n_in,
                              void* d_out, int out_size, void* d_ws, size_t ws_size,
                              hipStream_t stream) {
    (void)in_sizes; (void)n_in; (void)ws_size; (void)out_size;
    const float* phys    = (const float*)d_in[0];
    const float* latents = (const float*)d_in[1];
    const float* pos_emb = (const float*)d_in[2];
    const float* tokW    = (const float*)d_in[3];
    const float* tokb    = (const float*)d_in[4];
    const float* physW1  = (const float*)d_in[5];
    const float* physb1  = (const float*)d_in[6];
    const float* physW2  = (const float*)d_in[7];
    const float* physb2  = (const float*)d_in[8];
    const float* tn_g    = (const float*)d_in[9];
    const float* tn_b    = (const float*)d_in[10];
    const float* tiW     = (const float*)d_in[11];
    const float* tib     = (const float*)d_in[12];
    const float* toW     = (const float*)d_in[13];
    const float* tob     = (const float*)d_in[14];
    const float* cn_g    = (const float*)d_in[15];
    const float* cn_b    = (const float*)d_in[16];
    const float* ciW     = (const float*)d_in[17];
    const float* cib     = (const float*)d_in[18];
    const float* coW     = (const float*)d_in[19];
    const float* cob     = (const float*)d_in[20];
    const float* hn_g    = (const float*)d_in[21];
    const float* hn_b    = (const float*)d_in[22];
    const float* headW   = (const float*)d_in[23];
    const float* headb   = (const float*)d_in[24];

    lno_prep<<<dim3(256), dim3(256), 0, stream>>>(tiW, toW, ciW, coW, physW2, (short*)d_ws);
    // p pre-pass into d_out (B*T = 524288 waves; 4 waves/block)
    lno_phys<<<dim3(131072), dim3(256), 0, stream>>>(phys, physW1, physb1, physW2, physb2,
                                                     (short*)d_out);
    // scan: 256 blocks (1/CU), 8 waves/block = 8 independent batches
    lno_scan<<<dim3(256), dim3(512), 0, stream>>>(
        latents, pos_emb, tokW, tokb, tn_g, tn_b, tib, tob,
        cn_g, cn_b, cib, cob, hn_g, hn_b, headW, headb,
        (const short*)d_ws, (const short*)d_out, (float*)d_out);
}